// Round 19
// baseline (285.945 us; speedup 1.0000x reference)
//
#include <hip/hip_runtime.h>
#include <hip/hip_bf16.h>
#include <math.h>

#define NB 32
#define NT 2048
#define NC 1024
#define NM 131072
#define TOPK 8
#define NSB 256             // scores grid (1 block/CU)
#define ROWS_PB 512         // rows per block
#define NP 32               // panels per block (16 rows x 1024 cols = 64 KB)
#define SLOTF 260           // LDS slot stride (floats): 1 KB data + 16 B pad
#define TILEF (4 * 16 * SLOTF)       // one panel buffer: 16,640 floats
#define SCOFF (2 * TILEF)            // sc base: 33,280
#define SMEMF (SCOFF + 4 * 32 * 17)  // 35,456 floats = 141,824 B

typedef __attribute__((ext_vector_type(8))) short s16x8;   // 8 bf16 = 16 B
typedef __attribute__((ext_vector_type(4))) float f32x4;   // MFMA acc
typedef __attribute__((ext_vector_type(4))) int i32x4;

// ws layout (float offsets). candS/candI OVERLAY part (part dead after mean_finalize_k).
#define OFF_PART 0
#define OFF_CS   0                   // 32*256*8 = 65536 floats
#define OFF_CI   65536               // ends 131072 < part's 1048576
#define OFF_MEAN 1048576
#define OFF_Q    (OFF_MEAN + 32768)
#define OFF_QB   (OFF_Q + 32768)     // 4096 s16x8 = 64 KB

__device__ __forceinline__ unsigned short f2bf(float f) {
    unsigned u = __float_as_uint(f);
    unsigned r = (u + 0x7FFFu + ((u >> 16) & 1u)) >> 16;
    return (unsigned short)r;
}

__global__ __launch_bounds__(256) void mean_partial_k(const float* __restrict__ seg,
                                                      float* __restrict__ part) {
    int blk = blockIdx.x;            // 1024 = 32 b * 32 tc
    int b = blk >> 5, tc = blk & 31;
    int tid = threadIdx.x;
    const float4* src = (const float4*)(seg + ((size_t)b * NT + (size_t)tc * 64) * NC);
    float4 acc = make_float4(0.f, 0.f, 0.f, 0.f);
#pragma unroll 4
    for (int t = 0; t < 64; ++t) {
        float4 v = src[(size_t)t * 256 + tid];
        acc.x += v.x; acc.y += v.y; acc.z += v.z; acc.w += v.w;
    }
    ((float4*)(part + ((size_t)b * 32 + tc) * NC))[tid] = acc;
}

__global__ __launch_bounds__(256) void mean_finalize_k(const float* __restrict__ part,
                                                       float* __restrict__ mean) {
    int i = blockIdx.x * 256 + threadIdx.x;   // 32768
    int b = i >> 10, c = i & 1023;
    float s = 0.f;
#pragma unroll
    for (int tc = 0; tc < 32; ++tc) s += part[((size_t)b * 32 + tc) * NC + c];
    mean[i] = s * (1.0f / NT);
}

__global__ __launch_bounds__(256) void qproj_k(const float* __restrict__ mean,
                                               const float* __restrict__ Wq,
                                               const float* __restrict__ bq,
                                               float* __restrict__ q) {
    int wave = (blockIdx.x * 256 + threadIdx.x) >> 6;   // 2048 waves
    int lane = threadIdx.x & 63;
    int o0 = wave * 16;
    for (int j = 0; j < 16; ++j) {
        int o = o0 + j;                 // < 32768
        int b = o >> 10, i = o & 1023;
        const float4* wr = (const float4*)(Wq + (size_t)i * NC);
        const float4* mr = (const float4*)(mean + (size_t)b * NC);
        float acc = 0.f;
#pragma unroll
        for (int e = 0; e < 4; ++e) {
            float4 w4 = wr[lane * 4 + e];
            float4 m4 = mr[lane * 4 + e];
            acc += w4.x * m4.x + w4.y * m4.y + w4.z * m4.z + w4.w * m4.w;
        }
#pragma unroll
        for (int off = 32; off; off >>= 1) acc += __shfl_xor(acc, off);
        if (lane == 0) q[o] = acc + bq[i];
    }
}

// qb[(ksg*2+n)*64 + lane][e] = bf16(q[n*16+(lane&15)][ksg*32+(lane>>4)*8+e])
__global__ __launch_bounds__(256) void qbf_k(const float* __restrict__ q,
                                             s16x8* __restrict__ qb) {
    int idx = blockIdx.x * 256 + threadIdx.x;   // 4096
    int lane = idx & 63, n = (idx >> 6) & 1, ks = idx >> 7;
    int b = n * 16 + (lane & 15);
    int k0 = ks * 32 + ((lane >> 4) << 3);
    s16x8 v;
#pragma unroll
    for (int e = 0; e < 8; ++e) v[e] = (short)f2bf(q[(size_t)b * NC + k0 + e]);
    qb[idx] = v;
}

#define BUBBLE8(v, vi, s, si)                                   \
    {                                                           \
        float _v = (v); int _vi = (vi);                         \
        _Pragma("unroll")                                       \
        for (int _u = 0; _u < 8; ++_u) {                        \
            bool _gt = _v > s[_u];                               \
            float _ts = _gt ? _v : s[_u];                       \
            int _ti = _gt ? _vi : si[_u];                       \
            _v = _gt ? s[_u] : _v;                              \
            _vi = _gt ? si[_u] : _vi;                           \
            s[_u] = _ts; si[_u] = _ti;                          \
        }                                                       \
    }

#define BUBBLE8F(v, s)                                          \
    {                                                           \
        float _v = (v);                                         \
        _Pragma("unroll")                                       \
        for (int _u = 0; _u < 8; ++_u) {                        \
            bool _gt = _v > s[_u];                               \
            float _ts = _gt ? _v : s[_u];                       \
            _v = _gt ? s[_u] : _v;                              \
            s[_u] = _ts;                                        \
        }                                                       \
    }

// Reg-staged sequential-panel MFMA scores, NO-DRAIN barriers. grid 256
// (1 block/CU), 512 threads = 8 waves (b-tile n x k-quarter kh). Block owns
// 512 consecutive rows (2 MB); each 64 KB panel loaded flat-sequentially into
// REGISTERS (thread tid: float4 at flat i*512+tid — the mean_partial pattern),
// then ds_written to padded [c][r] slots. KEY FIX vs R16: raw s_barrier with
// lgkmcnt(0) ONLY — no vmcnt drain — so LOADR(p+1) stays in flight across all
// barriers and lands a full panel-period before WRITEL(p+1)'s register wait
// (compiler emits vmcnt(8), old loads only). qf: 8 fragments, loaded once.
__global__ __launch_bounds__(512, 1) void scores_mfma_k(const float* __restrict__ memb,
                                                        const s16x8* __restrict__ qb,
                                                        float* __restrict__ candS,
                                                        int* __restrict__ candI) {
    extern __shared__ __align__(16) float smemf[];   // SMEMF floats
    int tid = threadIdx.x, lane = tid & 63, ws = tid >> 6;
    int n = ws & 1, kh = ws >> 1;                    // b-tile, k-quarter
    size_t mb0 = (size_t)blockIdx.x * ROWS_PB;
    const float4* gbase = (const float4*)(memb + mb0 * NC);

    float s8[8];
#pragma unroll
    for (int u = 0; u < 8; ++u) s8[u] = -INFINITY;

    // qf: fixed per wave (k-quarter kh, b-tile n) — loaded once, 32 VGPR
    s16x8 qf[8];
#pragma unroll
    for (int s = 0; s < 8; ++s)
        qf[s] = qb[(((kh * 8 + s) * 2) + n) * 64 + lane];

    // thread's 8 flat float4 positions per panel: f = i*512 + tid
    // row r = f>>8, chunk c = (f>>6)&3, off = f&63; slot = (c*16+r)*SLOTF
    int lwoff[8];
#pragma unroll
    for (int i = 0; i < 8; ++i) {
        int f = i * 512 + tid;
        lwoff[i] = (((f >> 6) & 3) * 16 + (f >> 8)) * SLOTF + (f & 63) * 4;
    }

#define LOADR(dst_, p_) { const float4* gp = gbase + (size_t)(p_) * 4096;             \
    _Pragma("unroll") for (int i_ = 0; i_ < 8; ++i_)                                  \
        dst_[i_] = gp[i_ * 512 + tid];                                                \
    __builtin_amdgcn_sched_barrier(0); }

#define WRITEL(src_, buf_) { float* lb = smemf + (buf_) * TILEF;                      \
    _Pragma("unroll") for (int i_ = 0; i_ < 8; ++i_)                                  \
        *(float4*)(lb + lwoff[i_]) = src_[i_];                                        \
    __builtin_amdgcn_sched_barrier(0); }

#define DOPANEL(p_, rcur_, rnext_) {                                                  \
    __builtin_amdgcn_s_barrier();          /* B1: buf (p_&1) free, sc scan done */    \
    __builtin_amdgcn_sched_barrier(0);                                                \
    if ((p_) + 1 < NP) LOADR(rnext_, (p_) + 1);   /* issue next panel loads FIRST */  \
    WRITEL(rcur_, (p_) & 1);               /* waits only on OLD loads (vmcnt 8) */    \
    asm volatile("s_waitcnt lgkmcnt(0)" ::: "memory");                                \
    __builtin_amdgcn_sched_barrier(0);                                                \
    __builtin_amdgcn_s_barrier();          /* B2: panel p_ visible */                 \
    __builtin_amdgcn_sched_barrier(0);                                                \
    f32x4 acc = (f32x4){0.f, 0.f, 0.f, 0.f};                                          \
    const float* tb = smemf + ((p_) & 1) * TILEF;                                     \
    _Pragma("unroll") for (int s = 0; s < 8; ++s) {                                   \
        int ksg = kh * 8 + s;                                                         \
        const float* ap = tb + ((ksg >> 3) * 16 + (lane & 15)) * SLOTF                \
                        + (ksg & 7) * 32 + ((lane >> 4) << 3);                        \
        uint4 lo = *(const uint4*)(ap);                                               \
        uint4 hi = *(const uint4*)(ap + 4);                                           \
        i32x4 ai;                                                                     \
        ai[0] = __builtin_amdgcn_perm(lo.y, lo.x, 0x07060302u);                       \
        ai[1] = __builtin_amdgcn_perm(lo.w, lo.z, 0x07060302u);                       \
        ai[2] = __builtin_amdgcn_perm(hi.y, hi.x, 0x07060302u);                       \
        ai[3] = __builtin_amdgcn_perm(hi.w, hi.z, 0x07060302u);                       \
        s16x8 a = __builtin_bit_cast(s16x8, ai);                                      \
        acc = __builtin_amdgcn_mfma_f32_16x16x32_bf16(a, qf[s], acc, 0, 0, 0);        \
    }                                                                                 \
    {   /* partials -> sc[kh][b][m]; D layout m89: col=lane&15->b, row=(lane>>4)*4+j->m */ \
        int bcol = n * 16 + (lane & 15);                                              \
        int mrow = (lane >> 4) << 2;                                                  \
        _Pragma("unroll") for (int j = 0; j < 4; ++j)                                 \
            smemf[SCOFF + (kh * 32 + bcol) * 17 + mrow + j] = acc[j];                 \
    }                                                                                 \
    asm volatile("s_waitcnt lgkmcnt(0)" ::: "memory");                                \
    __builtin_amdgcn_sched_barrier(0);                                                \
    __builtin_amdgcn_s_barrier();          /* B3: sc visible */                       \
    __builtin_amdgcn_sched_barrier(0);                                                \
    {   /* scan: thread owns (b=tid>>4, m=tid&15); sum 4 k-quarters; embed 9-bit */   \
        int b_ = tid >> 4, m_ = tid & 15;                                             \
        float v = smemf[SCOFF + b_ * 17 + m_]                                         \
                + smemf[SCOFF + (32 + b_) * 17 + m_]                                  \
                + smemf[SCOFF + (64 + b_) * 17 + m_]                                  \
                + smemf[SCOFF + (96 + b_) * 17 + m_];                                 \
        unsigned uu = (__float_as_uint(v) & ~0x1FFu) | (unsigned)((p_) * 16 + m_);    \
        BUBBLE8F(__uint_as_float(uu), s8);                                            \
    } }

    float4 rA[8], rB[8];
    LOADR(rA, 0);
    for (int p = 0; p < NP; p += 2) {
        DOPANEL(p, rA, rB);
        DOPANEL(p + 1, rB, rA);
    }
#undef LOADR
#undef WRITEL
#undef DOPANEL

    // block merge: 512 per-thread lists -> per-b top-8 (float-only tree)
    {
        __syncthreads();
        float* cs = smemf;                    // [512][9] = 4608 floats
#pragma unroll
        for (int u = 0; u < 8; ++u) cs[tid * 9 + u] = s8[u];
        __syncthreads();
        float* csA = smemf + 4608;            // [128][9]
        if (tid < 128) {
            float s2[8];
#pragma unroll
            for (int u = 0; u < 8; ++u) s2[u] = -INFINITY;
            int t0 = (tid >> 2) * 16 + (tid & 3) * 4;   // 4 lists of the same b
            for (int tt = 0; tt < 4; ++tt)
#pragma unroll
                for (int u = 0; u < 8; ++u)
                    BUBBLE8F(cs[(t0 + tt) * 9 + u], s2);
#pragma unroll
            for (int u = 0; u < 8; ++u) csA[tid * 9 + u] = s2[u];
        }
        __syncthreads();
        if (tid < 32) {
            float s3[8];
#pragma unroll
            for (int u = 0; u < 8; ++u) s3[u] = -INFINITY;
            for (int j = 0; j < 32; ++j)
                BUBBLE8F(csA[(tid * 4 + (j >> 3)) * 9 + (j & 7)], s3);
#pragma unroll
            for (int u = 0; u < 8; ++u) {
                candS[((size_t)tid * NSB + blockIdx.x) * 8 + u] = s3[u] * 0.03125f;
                candI[((size_t)tid * NSB + blockIdx.x) * 8 + u] =
                    (int)mb0 + (int)(__float_as_uint(s3[u]) & 0x1FFu);
            }
        }
    }
}

// Per b: merge 2048 approx candidates -> 64 survivors -> EXACT f32 rescore ->
// exact top-8 + softmax + weighted gather.
__global__ __launch_bounds__(256) void finalize_k(const float* __restrict__ candS,
                                                  const int* __restrict__ candI,
                                                  const float* __restrict__ memb,
                                                  const float* __restrict__ q,
                                                  float* __restrict__ out) {
    __shared__ float cs[256 * 9];
    __shared__ int ci[256 * 9];
    __shared__ float csA[64 * 9];
    __shared__ int ciA[64 * 9];
    __shared__ float exsc[64];
    __shared__ int exid[64];
    __shared__ float wgt[8];
    __shared__ int widx[8];
    int b = blockIdx.x, tid = threadIdx.x;
    const float* S = candS + (size_t)b * (NSB * 8);
    const int* I = candI + (size_t)b * (NSB * 8);

    {   // A: 256 threads x 8 candidates
        float s[8]; int si[8];
#pragma unroll
        for (int u = 0; u < 8; ++u) { s[u] = -INFINITY; si[u] = -1; }
        for (int j = 0; j < 8; ++j)
            BUBBLE8(S[tid * 8 + j], I[tid * 8 + j], s, si);
#pragma unroll
        for (int u = 0; u < 8; ++u) { cs[tid * 9 + u] = s[u]; ci[tid * 9 + u] = si[u]; }
    }
    __syncthreads();
    if (tid < 64) {   // B: merge 4 lists
        float s[8]; int si[8];
#pragma unroll
        for (int u = 0; u < 8; ++u) { s[u] = -INFINITY; si[u] = -1; }
        for (int tt = 0; tt < 4; ++tt)
#pragma unroll
            for (int u = 0; u < 8; ++u)
                BUBBLE8(cs[(tid * 4 + tt) * 9 + u], ci[(tid * 4 + tt) * 9 + u], s, si);
#pragma unroll
        for (int u = 0; u < 8; ++u) { csA[tid * 9 + u] = s[u]; ciA[tid * 9 + u] = si[u]; }
    }
    __syncthreads();
    if (tid < 8) {    // C: merge 8 lists -> 64 survivors (superset of true top-8)
        float s[8]; int si[8];
#pragma unroll
        for (int u = 0; u < 8; ++u) { s[u] = -INFINITY; si[u] = -1; }
        for (int tt = 0; tt < 8; ++tt)
#pragma unroll
            for (int u = 0; u < 8; ++u)
                BUBBLE8(csA[(tid * 8 + tt) * 9 + u], ciA[(tid * 8 + tt) * 9 + u], s, si);
#pragma unroll
        for (int u = 0; u < 8; ++u) exid[tid * 8 + u] = si[u];
    }
    __syncthreads();
    {   // D: exact f32 rescore; wave w -> candidates w*16..+15
        int w = tid >> 6, lane = tid & 63;
        const float4* qr = (const float4*)(q + (size_t)b * NC);
        for (int i = 0; i < 16; ++i) {
            int c = w * 16 + i;
            int row = exid[c];
            const float4* mr = (const float4*)(memb + (size_t)row * NC);
            float d = 0.f;
#pragma unroll
            for (int e = 0; e < 4; ++e) {
                float4 m4 = mr[e * 64 + lane];
                float4 q4 = qr[e * 64 + lane];
                d += m4.x * q4.x + m4.y * q4.y + m4.z * q4.z + m4.w * q4.w;
            }
#pragma unroll
            for (int off = 32; off; off >>= 1) d += __shfl_xor(d, off);
            if (lane == 0) exsc[c] = d * 0.03125f;
        }
    }
    __syncthreads();
    if (tid == 0) {   // E: exact top-8 of 64 + softmax
        float s4[8]; int si4[8];
#pragma unroll
        for (int u = 0; u < 8; ++u) { s4[u] = -INFINITY; si4[u] = -1; }
        for (int j = 0; j < 64; ++j)
            BUBBLE8(exsc[j], exid[j], s4, si4);
        float m = s4[0], sum = 0.f, w[8];
#pragma unroll
        for (int u = 0; u < 8; ++u) { w[u] = __expf(s4[u] - m); sum += w[u]; }
        float inv = 1.0f / sum;
#pragma unroll
        for (int u = 0; u < 8; ++u) { wgt[u] = w[u] * inv; widx[u] = si4[u]; }
    }
    __syncthreads();
    {   // F: weighted gather
        float wv[8]; int ix[8];
#pragma unroll
        for (int u = 0; u < 8; ++u) { wv[u] = wgt[u]; ix[u] = widx[u]; }
        float4 o = make_float4(0.f, 0.f, 0.f, 0.f);
#pragma unroll
        for (int u = 0; u < 8; ++u) {
            float4 r = ((const float4*)(memb + (size_t)ix[u] * NC))[tid];
            o.x = fmaf(wv[u], r.x, o.x);
            o.y = fmaf(wv[u], r.y, o.y);
            o.z = fmaf(wv[u], r.z, o.z);
            o.w = fmaf(wv[u], r.w, o.w);
        }
        ((float4*)(out + (size_t)b * NC))[tid] = o;
    }
}

extern "C" void kernel_launch(void* const* d_in, const int* in_sizes, int n_in,
                              void* d_out, int out_size, void* d_ws, size_t ws_size,
                              hipStream_t stream) {
    const float* seg  = (const float*)d_in[0];
    const float* Wq   = (const float*)d_in[1];
    const float* bq   = (const float*)d_in[2];
    const float* memb = (const float*)d_in[3];
    float* ws = (float*)d_ws;
    float* part  = ws + OFF_PART;
    float* mean  = ws + OFF_MEAN;
    float* q     = ws + OFF_Q;
    s16x8* qb    = (s16x8*)(ws + OFF_QB);
    float* candS = ws + OFF_CS;           // overlays part (safe: part dead by then)
    int*   candI = (int*)(ws + OFF_CI);
    float* out = (float*)d_out;

    (void)hipFuncSetAttribute((const void*)scores_mfma_k,
                              hipFuncAttributeMaxDynamicSharedMemorySize,
                              SMEMF * 4);

    mean_partial_k<<<NB * 32, 256, 0, stream>>>(seg, part);
    mean_finalize_k<<<(NB * NC) / 256, 256, 0, stream>>>(part, mean);
    qproj_k<<<512, 256, 0, stream>>>(mean, Wq, bq, q);
    qbf_k<<<16, 256, 0, stream>>>(q, qb);
    scores_mfma_k<<<NSB, 512, SMEMF * 4, stream>>>(memb, qb, candS, candI);
    finalize_k<<<NB, 256, 0, stream>>>(candS, candI, memb, q, out);
}

// Round 20
// 204.595 us; speedup vs baseline: 1.3976x; 1.3976x over previous
//
#include <hip/hip_runtime.h>
#include <hip/hip_bf16.h>
#include <math.h>

#define NB 32
#define NT 2048
#define NC 1024
#define NM 131072
#define TOPK 8
#define NSB 256             // scores grid (1 block/CU)
#define ROWS_PB 512         // rows per block
#define NP 32               // panels per block (16 rows each)
#define SLOTF 260           // LDS slot stride (floats): 1 KB data + 16 B pad
#define TILEF (4 * 16 * SLOTF)       // one panel buffer: 16,640 floats
#define SCOFF (2 * TILEF)            // sc base: 33,280
#define SMEMF (SCOFF + 2 * 32 * 17)  // 34,368 floats = 137,472 B

typedef __attribute__((ext_vector_type(8))) short s16x8;   // 8 bf16 = 16 B
typedef __attribute__((ext_vector_type(4))) float f32x4;   // MFMA acc
typedef __attribute__((ext_vector_type(4))) int i32x4;

// ws layout (float offsets). candS/candI OVERLAY part (part dead after mean_finalize_k).
#define OFF_PART 0
#define OFF_CS   0                   // 32*256*8 = 65536 floats
#define OFF_CI   65536               // ends 131072 < part's 1048576
#define OFF_MEAN 1048576
#define OFF_Q    (OFF_MEAN + 32768)
#define OFF_QB   (OFF_Q + 32768)     // 4096 s16x8 = 64 KB

__device__ __forceinline__ unsigned short f2bf(float f) {
    unsigned u = __float_as_uint(f);
    unsigned r = (u + 0x7FFFu + ((u >> 16) & 1u)) >> 16;
    return (unsigned short)r;
}

__device__ __forceinline__ void gl_lds16(const float* g, float* l) {
    // one instruction: 64 lanes x 16B -> LDS base + lane*16 (contiguous 1 KB)
    __builtin_amdgcn_global_load_lds((const __attribute__((address_space(1))) void*)g,
                                     (__attribute__((address_space(3))) void*)l, 16, 0, 0);
}

__global__ __launch_bounds__(256) void mean_partial_k(const float* __restrict__ seg,
                                                      float* __restrict__ part) {
    int blk = blockIdx.x;            // 1024 = 32 b * 32 tc
    int b = blk >> 5, tc = blk & 31;
    int tid = threadIdx.x;
    const float4* src = (const float4*)(seg + ((size_t)b * NT + (size_t)tc * 64) * NC);
    float4 acc = make_float4(0.f, 0.f, 0.f, 0.f);
#pragma unroll 4
    for (int t = 0; t < 64; ++t) {
        float4 v = src[(size_t)t * 256 + tid];
        acc.x += v.x; acc.y += v.y; acc.z += v.z; acc.w += v.w;
    }
    ((float4*)(part + ((size_t)b * 32 + tc) * NC))[tid] = acc;
}

__global__ __launch_bounds__(256) void mean_finalize_k(const float* __restrict__ part,
                                                       float* __restrict__ mean) {
    int i = blockIdx.x * 256 + threadIdx.x;   // 32768
    int b = i >> 10, c = i & 1023;
    float s = 0.f;
#pragma unroll
    for (int tc = 0; tc < 32; ++tc) s += part[((size_t)b * 32 + tc) * NC + c];
    mean[i] = s * (1.0f / NT);
}

__global__ __launch_bounds__(256) void qproj_k(const float* __restrict__ mean,
                                               const float* __restrict__ Wq,
                                               const float* __restrict__ bq,
                                               float* __restrict__ q) {
    int wave = (blockIdx.x * 256 + threadIdx.x) >> 6;   // 2048 waves
    int lane = threadIdx.x & 63;
    int o0 = wave * 16;
    for (int j = 0; j < 16; ++j) {
        int o = o0 + j;                 // < 32768
        int b = o >> 10, i = o & 1023;
        const float4* wr = (const float4*)(Wq + (size_t)i * NC);
        const float4* mr = (const float4*)(mean + (size_t)b * NC);
        float acc = 0.f;
#pragma unroll
        for (int e = 0; e < 4; ++e) {
            float4 w4 = wr[lane * 4 + e];
            float4 m4 = mr[lane * 4 + e];
            acc += w4.x * m4.x + w4.y * m4.y + w4.z * m4.z + w4.w * m4.w;
        }
#pragma unroll
        for (int off = 32; off; off >>= 1) acc += __shfl_xor(acc, off);
        if (lane == 0) q[o] = acc + bq[i];
    }
}

// qb[(ksg*2+n)*64 + lane][e] = bf16(q[n*16+(lane&15)][ksg*32+(lane>>4)*8+e])
__global__ __launch_bounds__(256) void qbf_k(const float* __restrict__ q,
                                             s16x8* __restrict__ qb) {
    int idx = blockIdx.x * 256 + threadIdx.x;   // 4096
    int lane = idx & 63, n = (idx >> 6) & 1, ks = idx >> 7;
    int b = n * 16 + (lane & 15);
    int k0 = ks * 32 + ((lane >> 4) << 3);
    s16x8 v;
#pragma unroll
    for (int e = 0; e < 8; ++e) v[e] = (short)f2bf(q[(size_t)b * NC + k0 + e]);
    qb[idx] = v;
}

#define BUBBLE8(v, vi, s, si)                                   \
    {                                                           \
        float _v = (v); int _vi = (vi);                         \
        _Pragma("unroll")                                       \
        for (int _u = 0; _u < 8; ++_u) {                        \
            bool _gt = _v > s[_u];                               \
            float _ts = _gt ? _v : s[_u];                       \
            int _ti = _gt ? _vi : si[_u];                       \
            _v = _gt ? s[_u] : _v;                              \
            _vi = _gt ? si[_u] : _vi;                           \
            s[_u] = _ts; si[_u] = _ti;                          \
        }                                                       \
    }

#define BUBBLE8F(v, s)                                          \
    {                                                           \
        float _v = (v);                                         \
        _Pragma("unroll")                                       \
        for (int _u = 0; _u < 8; ++_u) {                        \
            bool _gt = _v > s[_u];                               \
            float _ts = _gt ? _v : s[_u];                       \
            _v = _gt ? s[_u] : _v;                              \
            s[_u] = _ts;                                        \
        }                                                       \
    }

// Sequential-panel MFMA scores (best-known config, R15/R18). grid 256
// (1 block/CU), 4 waves = (b-tile n x k-half kh). Block owns 512 consecutive
// rows = 2 MB, fetched as one purely sequential stream of 16-row panels
// (64 KB) via 16 gl_lds16 per panel, 16-B padded [c][r] slots. Double buffer
// + counted vmcnt(16): panel p+1 always in flight. qf fragments
// PANEL-INVARIANT per wave (fixed k-half) -> loaded once. Per panel: 16
// MFMA/wave, cross-wave k-sum via sc, 9-bit local-index mantissa-embed top-8.
__global__ __launch_bounds__(256, 1) void scores_mfma_k(const float* __restrict__ memb,
                                                        const s16x8* __restrict__ qb,
                                                        float* __restrict__ candS,
                                                        int* __restrict__ candI) {
    extern __shared__ __align__(16) float smemf[];   // SMEMF floats (137,472 B)
    int tid = threadIdx.x, lane = tid & 63, ws = tid >> 6;
    int n = ws & 1, kh = ws >> 1;
    size_t mb0 = (size_t)blockIdx.x * ROWS_PB;

    float s8[8];
#pragma unroll
    for (int u = 0; u < 8; ++u) s8[u] = -INFINITY;

#define TISSUE(p_) { float* lb = smemf + ((p_) & 1) * TILEF;                          \
    const float* gb = memb + (mb0 + (size_t)(p_) * 16) * NC + lane * 4;               \
    _Pragma("unroll") for (int i_ = 0; i_ < 16; ++i_) {                               \
        int r_ = ws * 4 + (i_ >> 2), c_ = i_ & 3;                                     \
        gl_lds16(gb + (size_t)r_ * NC + c_ * 256, lb + (c_ * 16 + r_) * SLOTF); } }

    // qf: fixed per wave (its k-half, its b-tile) — loaded once
    s16x8 qf[16];
#pragma unroll
    for (int s = 0; s < 16; ++s)
        qf[s] = qb[((kh * 16 + s) * 2 + n) * 64 + lane];

    TISSUE(0);
    TISSUE(1);

    for (int p = 0; p < NP; ++p) {
        if (p + 1 < NP) { asm volatile("s_waitcnt vmcnt(16)" ::: "memory"); }
        else            { asm volatile("s_waitcnt vmcnt(0)" ::: "memory"); }
        __builtin_amdgcn_sched_barrier(0);
        __builtin_amdgcn_s_barrier();         // panel p visible to all waves
        __builtin_amdgcn_sched_barrier(0);

        // compute panel p: 16 ks steps of this wave's k-half
        f32x4 acc = (f32x4){0.f, 0.f, 0.f, 0.f};
        const float* tb = smemf + (p & 1) * TILEF;
#pragma unroll
        for (int s = 0; s < 16; ++s) {
            int ksg = kh * 16 + s;
            const float* ap = tb + ((ksg >> 3) * 16 + (lane & 15)) * SLOTF
                            + (ksg & 7) * 32 + ((lane >> 4) << 3);
            uint4 lo = *(const uint4*)(ap);
            uint4 hi = *(const uint4*)(ap + 4);
            i32x4 ai;
            ai[0] = __builtin_amdgcn_perm(lo.y, lo.x, 0x07060302u);
            ai[1] = __builtin_amdgcn_perm(lo.w, lo.z, 0x07060302u);
            ai[2] = __builtin_amdgcn_perm(hi.y, hi.x, 0x07060302u);
            ai[3] = __builtin_amdgcn_perm(hi.w, hi.z, 0x07060302u);
            s16x8 a = __builtin_bit_cast(s16x8, ai);
            acc = __builtin_amdgcn_mfma_f32_16x16x32_bf16(a, qf[s], acc, 0, 0, 0);
        }

        // partials -> sc[kh][b][m] (D layout m89: col=lane&15 -> b, row=(lane>>4)*4+j -> m)
        {
            int bcol = n * 16 + (lane & 15);
            int mrow = (lane >> 4) << 2;
#pragma unroll
            for (int j = 0; j < 4; ++j)
                smemf[SCOFF + (kh * 32 + bcol) * 17 + mrow + j] = acc[j];
        }
        asm volatile("s_waitcnt lgkmcnt(0)" ::: "memory");
        __builtin_amdgcn_sched_barrier(0);
        __builtin_amdgcn_s_barrier();
        __builtin_amdgcn_sched_barrier(0);

        // scan: thread owns (b=tid>>3, pq=tid&7), rows {pq, pq+8}; sum 2 k-halves;
        // embed 9-bit local idx (p*16+m) in low mantissa bits
        {
            int b = tid >> 3, pq = tid & 7;
#pragma unroll
            for (int rr = 0; rr < 2; ++rr) {
                int m = pq + rr * 8;
                float v = smemf[SCOFF + b * 17 + m]
                        + smemf[SCOFF + (32 + b) * 17 + m];
                unsigned uu = (__float_as_uint(v) & ~0x1FFu) | (unsigned)(p * 16 + m);
                BUBBLE8F(__uint_as_float(uu), s8);
            }
        }
        __builtin_amdgcn_sched_barrier(0);
        __builtin_amdgcn_s_barrier();         // sc reads + tile reads done; bufs free
        __builtin_amdgcn_sched_barrier(0);

        if (p + 2 < NP) TISSUE(p + 2);
    }
#undef TISSUE

    // block-level merge: 256 per-thread lists -> per-b top-8 (float-only tree)
    {
        float* cs = smemf;                    // [256][9]
#pragma unroll
        for (int u = 0; u < 8; ++u) cs[tid * 9 + u] = s8[u];
        __syncthreads();
        float* csA = smemf + 2304;            // [64][9]
        if (tid < 64) {
            float s2[8];
#pragma unroll
            for (int u = 0; u < 8; ++u) s2[u] = -INFINITY;
            int t0 = (tid >> 1) * 8 + (tid & 1) * 4;
            for (int tt = 0; tt < 4; ++tt)
#pragma unroll
                for (int u = 0; u < 8; ++u)
                    BUBBLE8F(cs[(t0 + tt) * 9 + u], s2);
#pragma unroll
            for (int u = 0; u < 8; ++u) csA[tid * 9 + u] = s2[u];
        }
        __syncthreads();
        if (tid < 32) {
            float s3[8];
#pragma unroll
            for (int u = 0; u < 8; ++u) s3[u] = -INFINITY;
            for (int j = 0; j < 16; ++j)
                BUBBLE8F(csA[(tid * 2 + (j >> 3)) * 9 + (j & 7)], s3);
#pragma unroll
            for (int u = 0; u < 8; ++u) {
                candS[((size_t)tid * NSB + blockIdx.x) * 8 + u] = s3[u] * 0.03125f;
                candI[((size_t)tid * NSB + blockIdx.x) * 8 + u] =
                    (int)mb0 + (int)(__float_as_uint(s3[u]) & 0x1FFu);
            }
        }
    }
}

// Per b: merge 2048 approx candidates -> 64 survivors -> EXACT f32 rescore ->
// exact top-8 + softmax + weighted gather.
__global__ __launch_bounds__(256) void finalize_k(const float* __restrict__ candS,
                                                  const int* __restrict__ candI,
                                                  const float* __restrict__ memb,
                                                  const float* __restrict__ q,
                                                  float* __restrict__ out) {
    __shared__ float cs[256 * 9];
    __shared__ int ci[256 * 9];
    __shared__ float csA[64 * 9];
    __shared__ int ciA[64 * 9];
    __shared__ float exsc[64];
    __shared__ int exid[64];
    __shared__ float wgt[8];
    __shared__ int widx[8];
    int b = blockIdx.x, tid = threadIdx.x;
    const float* S = candS + (size_t)b * (NSB * 8);
    const int* I = candI + (size_t)b * (NSB * 8);

    {   // A: 256 threads x 8 candidates
        float s[8]; int si[8];
#pragma unroll
        for (int u = 0; u < 8; ++u) { s[u] = -INFINITY; si[u] = -1; }
        for (int j = 0; j < 8; ++j)
            BUBBLE8(S[tid * 8 + j], I[tid * 8 + j], s, si);
#pragma unroll
        for (int u = 0; u < 8; ++u) { cs[tid * 9 + u] = s[u]; ci[tid * 9 + u] = si[u]; }
    }
    __syncthreads();
    if (tid < 64) {   // B: merge 4 lists
        float s[8]; int si[8];
#pragma unroll
        for (int u = 0; u < 8; ++u) { s[u] = -INFINITY; si[u] = -1; }
        for (int tt = 0; tt < 4; ++tt)
#pragma unroll
            for (int u = 0; u < 8; ++u)
                BUBBLE8(cs[(tid * 4 + tt) * 9 + u], ci[(tid * 4 + tt) * 9 + u], s, si);
#pragma unroll
        for (int u = 0; u < 8; ++u) { csA[tid * 9 + u] = s[u]; ciA[tid * 9 + u] = si[u]; }
    }
    __syncthreads();
    if (tid < 8) {    // C: merge 8 lists -> 64 survivors (superset of true top-8)
        float s[8]; int si[8];
#pragma unroll
        for (int u = 0; u < 8; ++u) { s[u] = -INFINITY; si[u] = -1; }
        for (int tt = 0; tt < 8; ++tt)
#pragma unroll
            for (int u = 0; u < 8; ++u)
                BUBBLE8(csA[(tid * 8 + tt) * 9 + u], ciA[(tid * 8 + tt) * 9 + u], s, si);
#pragma unroll
        for (int u = 0; u < 8; ++u) exid[tid * 8 + u] = si[u];
    }
    __syncthreads();
    {   // D: exact f32 rescore; wave w -> candidates w*16..+15
        int w = tid >> 6, lane = tid & 63;
        const float4* qr = (const float4*)(q + (size_t)b * NC);
        for (int i = 0; i < 16; ++i) {
            int c = w * 16 + i;
            int row = exid[c];
            const float4* mr = (const float4*)(memb + (size_t)row * NC);
            float d = 0.f;
#pragma unroll
            for (int e = 0; e < 4; ++e) {
                float4 m4 = mr[e * 64 + lane];
                float4 q4 = qr[e * 64 + lane];
                d += m4.x * q4.x + m4.y * q4.y + m4.z * q4.z + m4.w * q4.w;
            }
#pragma unroll
            for (int off = 32; off; off >>= 1) d += __shfl_xor(d, off);
            if (lane == 0) exsc[c] = d * 0.03125f;
        }
    }
    __syncthreads();
    if (tid == 0) {   // E: exact top-8 of 64 + softmax
        float s4[8]; int si4[8];
#pragma unroll
        for (int u = 0; u < 8; ++u) { s4[u] = -INFINITY; si4[u] = -1; }
        for (int j = 0; j < 64; ++j)
            BUBBLE8(exsc[j], exid[j], s4, si4);
        float m = s4[0], sum = 0.f, w[8];
#pragma unroll
        for (int u = 0; u < 8; ++u) { w[u] = __expf(s4[u] - m); sum += w[u]; }
        float inv = 1.0f / sum;
#pragma unroll
        for (int u = 0; u < 8; ++u) { wgt[u] = w[u] * inv; widx[u] = si4[u]; }
    }
    __syncthreads();
    {   // F: weighted gather
        float wv[8]; int ix[8];
#pragma unroll
        for (int u = 0; u < 8; ++u) { wv[u] = wgt[u]; ix[u] = widx[u]; }
        float4 o = make_float4(0.f, 0.f, 0.f, 0.f);
#pragma unroll
        for (int u = 0; u < 8; ++u) {
            float4 r = ((const float4*)(memb + (size_t)ix[u] * NC))[tid];
            o.x = fmaf(wv[u], r.x, o.x);
            o.y = fmaf(wv[u], r.y, o.y);
            o.z = fmaf(wv[u], r.z, o.z);
            o.w = fmaf(wv[u], r.w, o.w);
        }
        ((float4*)(out + (size_t)b * NC))[tid] = o;
    }
}

extern "C" void kernel_launch(void* const* d_in, const int* in_sizes, int n_in,
                              void* d_out, int out_size, void* d_ws, size_t ws_size,
                              hipStream_t stream) {
    const float* seg  = (const float*)d_in[0];
    const float* Wq   = (const float*)d_in[1];
    const float* bq   = (const float*)d_in[2];
    const float* memb = (const float*)d_in[3];
    float* ws = (float*)d_ws;
    float* part  = ws + OFF_PART;
    float* mean  = ws + OFF_MEAN;
    float* q     = ws + OFF_Q;
    s16x8* qb    = (s16x8*)(ws + OFF_QB);
    float* candS = ws + OFF_CS;           // overlays part (safe: part dead by then)
    int*   candI = (int*)(ws + OFF_CI);
    float* out = (float*)d_out;

    (void)hipFuncSetAttribute((const void*)scores_mfma_k,
                              hipFuncAttributeMaxDynamicSharedMemorySize,
                              SMEMF * 4);

    mean_partial_k<<<NB * 32, 256, 0, stream>>>(seg, part);
    mean_finalize_k<<<(NB * NC) / 256, 256, 0, stream>>>(part, mean);
    qproj_k<<<512, 256, 0, stream>>>(mean, Wq, bq, q);
    qbf_k<<<16, 256, 0, stream>>>(q, qb);
    scores_mfma_k<<<NSB, 256, SMEMF * 4, stream>>>(memb, qb, candS, candI);
    finalize_k<<<NB, 256, 0, stream>>>(candS, candI, memb, q, out);
}